// Round 1
// baseline (1122.535 us; speedup 1.0000x reference)
//
#include <hip/hip_runtime.h>

#define BB 8
#define MM 4096
#define EE 2048
#define DD 128

typedef __attribute__((ext_vector_type(8))) short bfrag;   // 8 bf16
typedef __attribute__((ext_vector_type(4))) float ffrag;   // 4 f32

__device__ inline short f2bf(float x){
    unsigned u = __float_as_uint(x);
    u = (u + 0x7fffu + ((u >> 16) & 1u)) >> 16;   // RNE
    return (short)u;
}
__device__ inline float bf2f(short s){
    return __uint_as_float(((unsigned)(unsigned short)s) << 16);
}

// C[b, row, d] = sum_k A[b, row, k] * Bsrc[b, k, d]
// TRANS_A: A[row,k] = inc[b][k][row] (K = M, rows index E)   -> agg = inc^T @ feat
// !TRANS_A: A[row,k] = inc[b][row][k] (K = E, rows index M)  -> node = inc @ ef2
// inc is binary (exact in bf16); Bsrc is split hi/lo bf16 for ~fp32 accuracy.
template<bool TRANS_A>
__global__ __launch_bounds__(256) void big_mm(const float* __restrict__ inc_g,
                                              const float* __restrict__ B_g,
                                              float* __restrict__ C_g,
                                              int K)
{
    __shared__ alignas(16) short lA [64][72];    // [row][k], row stride 144B (16B-aligned, conflict-friendly)
    __shared__ alignas(16) short lBh[128][72];   // [d][k] hi
    __shared__ alignas(16) short lBl[128][72];   // [d][k] lo

    const int b     = blockIdx.y;
    const int nrows = gridDim.x * 64;
    const float* inc = inc_g + (size_t)b * MM * EE;
    const float* Bp  = B_g   + (size_t)b * K  * DD;
    float*       Cp  = C_g   + (size_t)b * nrows * DD;
    const int row0 = blockIdx.x * 64;

    const int t    = threadIdx.x;
    const int wave = t >> 6;
    const int lane = t & 63;
    const int fr   = lane & 15;   // m (A) / n (B) / col (D)
    const int q    = lane >> 4;   // quad

    ffrag acc[4][2] = {};         // wave tile: 64 rows x 32 cols

    float4 ra[4], rb[8];

    auto load_a = [&](int k0){
        #pragma unroll
        for (int i = 0; i < 4; i++){
            int idx = t + 256*i;                  // 1024 float4 = 64x64 tile
            if (TRANS_A){
                int kk = idx >> 4, e4 = idx & 15;
                ra[i] = *(const float4*)(inc + (size_t)(k0+kk)*EE + row0 + e4*4);
            } else {
                int ii = idx >> 4, k4 = idx & 15;
                ra[i] = *(const float4*)(inc + (size_t)(row0+ii)*EE + k0 + k4*4);
            }
        }
    };
    auto load_b = [&](int k0){
        #pragma unroll
        for (int i = 0; i < 8; i++){
            int idx = t + 256*i;                  // 2048 float4 = 64x128 tile
            int kk = idx >> 5, d4 = idx & 31;
            rb[i] = *(const float4*)(Bp + (size_t)(k0+kk)*DD + d4*4);
        }
    };
    auto store_lds = [&](){
        #pragma unroll
        for (int i = 0; i < 4; i++){
            int idx = t + 256*i;
            const float* v = (const float*)&ra[i];
            if (TRANS_A){
                int kk = idx >> 4, e4 = idx & 15;
                #pragma unroll
                for (int j = 0; j < 4; j++) lA[e4*4+j][kk] = f2bf(v[j]);
            } else {
                int ii = idx >> 4, k4 = idx & 15;
                short4 s4 = { f2bf(v[0]), f2bf(v[1]), f2bf(v[2]), f2bf(v[3]) };
                *(short4*)&lA[ii][k4*4] = s4;
            }
        }
        #pragma unroll
        for (int i = 0; i < 8; i++){
            int idx = t + 256*i;
            int kk = idx >> 5, d4 = idx & 31;
            const float* v = (const float*)&rb[i];
            #pragma unroll
            for (int j = 0; j < 4; j++){
                short hi = f2bf(v[j]);
                float lo = v[j] - bf2f(hi);
                lBh[d4*4+j][kk] = hi;
                lBl[d4*4+j][kk] = f2bf(lo);
            }
        }
    };

    const int nchunk = K >> 6;    // BK = 64
    load_a(0); load_b(0);
    for (int c = 0; c < nchunk; c++){
        __syncthreads();
        store_lds();
        __syncthreads();
        if (c + 1 < nchunk){ load_a((c+1) << 6); load_b((c+1) << 6); }  // prefetch overlaps MFMA
        #pragma unroll
        for (int h = 0; h < 2; h++){
            const int ko = h*32 + q*8;
            bfrag a[4], vh[2], vl[2];
            #pragma unroll
            for (int r = 0; r < 4; r++) a[r] = *(const bfrag*)&lA[r*16 + fr][ko];
            #pragma unroll
            for (int cc = 0; cc < 2; cc++){
                int col = wave*32 + cc*16 + fr;
                vh[cc] = *(const bfrag*)&lBh[col][ko];
                vl[cc] = *(const bfrag*)&lBl[col][ko];
            }
            #pragma unroll
            for (int r = 0; r < 4; r++)
                #pragma unroll
                for (int cc = 0; cc < 2; cc++){
                    acc[r][cc] = __builtin_amdgcn_mfma_f32_16x16x32_bf16(a[r], vh[cc], acc[r][cc], 0, 0, 0);
                    acc[r][cc] = __builtin_amdgcn_mfma_f32_16x16x32_bf16(a[r], vl[cc], acc[r][cc], 0, 0, 0);
                }
        }
    }
    // epilogue: D layout col = lane&15, row = quad*4 + reg  [m89-verified]
    #pragma unroll
    for (int r = 0; r < 4; r++)
        #pragma unroll
        for (int cc = 0; cc < 2; cc++){
            int col = wave*32 + cc*16 + fr;
            #pragma unroll
            for (int reg = 0; reg < 4; reg++){
                int row = row0 + r*16 + q*4 + reg;
                Cp[(size_t)row*DD + col] = acc[r][cc][reg];
            }
        }
}

// C[n, :] = A[n, :] @ W^T   (fp32, W is [128][128] row-major, C[n][c] = sum_k A[n][k]*W[c][k])
__global__ __launch_bounds__(256) void rowmm(const float* __restrict__ A,
                                             const float* __restrict__ W,
                                             float* __restrict__ C)
{
    __shared__ alignas(16) float lA[32][132];   // 33x16B rows
    __shared__ alignas(16) float lW[64][140];   // 35x16B rows, half of W per phase
    const int t = threadIdx.x;
    const int row0 = blockIdx.x * 32;
    const float4* A4 = (const float4*)A;
    const float4* W4 = (const float4*)W;

    #pragma unroll
    for (int i = 0; i < 4; i++){
        int idx = t + 256*i;                      // 1024 f4 = 32x128
        int r = idx >> 5, k4 = idx & 31;
        *(float4*)&lA[r][k4*4] = A4[(size_t)(row0+r)*32 + k4];
    }
    const int qq = t >> 5;    // 0..7 : rows qq, qq+8, qq+16, qq+24
    const int cc = t & 31;    // cols cc, cc+32 (phase-local)

    #pragma unroll
    for (int ph = 0; ph < 2; ph++){
        __syncthreads();
        #pragma unroll
        for (int i = 0; i < 8; i++){
            int idx = t + 256*i;                  // 2048 f4 = 64x128
            int c = idx >> 5, k4 = idx & 31;
            *(float4*)&lW[c][k4*4] = W4[(size_t)(ph*64 + c)*32 + k4];
        }
        __syncthreads();
        float s[4][2] = {};
        for (int k4 = 0; k4 < 32; k4++){
            float4 w0 = *(const float4*)&lW[cc][k4*4];
            float4 w1 = *(const float4*)&lW[cc+32][k4*4];
            #pragma unroll
            for (int j = 0; j < 4; j++){
                float4 a = *(const float4*)&lA[qq + 8*j][k4*4];
                s[j][0] += a.x*w0.x + a.y*w0.y + a.z*w0.z + a.w*w0.w;
                s[j][1] += a.x*w1.x + a.y*w1.y + a.z*w1.z + a.w*w1.w;
            }
        }
        #pragma unroll
        for (int j = 0; j < 4; j++){
            size_t ro = (size_t)(row0 + qq + 8*j) * DD + ph*64;
            C[ro + cc]      = s[j][0];
            C[ro + cc + 32] = s[j][1];
        }
    }
}

// in-place: eatt[b,e,d] -> agg[b,e,d] * softmax_over_e(eatt)[b,e,d]
__global__ __launch_bounds__(256) void softmax_mul(float* __restrict__ eatt,
                                                   const float* __restrict__ agg)
{
    const int b  = blockIdx.x >> 2;
    const int d0 = (blockIdx.x & 3) * 32;
    const int t  = threadIdx.x;
    const int dl = t & 31;
    const int er = t >> 5;   // 0..7
    const size_t base = (size_t)b * EE * DD + d0 + dl;

    __shared__ float red[8][33];

    float mx = -1e30f;
    for (int e = er; e < EE; e += 8) mx = fmaxf(mx, eatt[base + (size_t)e*DD]);
    red[er][dl] = mx;
    __syncthreads();
    mx = -1e30f;
    #pragma unroll
    for (int j = 0; j < 8; j++) mx = fmaxf(mx, red[j][dl]);
    __syncthreads();

    float sm = 0.f;
    for (int e = er; e < EE; e += 8) sm += __expf(eatt[base + (size_t)e*DD] - mx);
    red[er][dl] = sm;
    __syncthreads();
    sm = 0.f;
    #pragma unroll
    for (int j = 0; j < 8; j++) sm += red[j][dl];
    const float inv = 1.f / sm;

    for (int e = er; e < EE; e += 8){
        size_t ix = base + (size_t)e*DD;
        eatt[ix] = agg[ix] * __expf(eatt[ix] - mx) * inv;
    }
}

extern "C" void kernel_launch(void* const* d_in, const int* in_sizes, int n_in,
                              void* d_out, int out_size, void* d_ws, size_t ws_size,
                              hipStream_t stream)
{
    const float* feat = (const float*)d_in[0];   // [8,4096,128]
    const float* inc  = (const float*)d_in[1];   // [8,4096,2048]
    const float* vWa  = (const float*)d_in[2];   // [128,128]
    const float* vWp  = (const float*)d_in[3];
    const float* eWp  = (const float*)d_in[6];
    // vc_alpha / ec_Wa / ec_alpha / n_layers unused: the layer recursion is a
    // fixed point (prev == base every layer), and ec_Wa feeds dead code.

    float* node_out = (float*)d_out;                         // [8,4096,128]
    float* edge_out = node_out + (size_t)BB * MM * DD;       // [8,2048,128]

    float* buf0 = (float*)d_ws;                  // agg, later ef2   [8,2048,128]
    float* buf1 = buf0 + (size_t)BB * EE * DD;   // eatt, then P     [8,2048,128]

    dim3 blk(256);

    // 1. agg = inc^T @ feat          (K = M = 4096)
    big_mm<true ><<<dim3(EE/64, BB), blk, 0, stream>>>(inc, feat, buf0, MM);
    // 2. eatt = agg @ vWa^T          (e_att == (inc^T @ (feat@Wa^T)) by associativity)
    rowmm<<<dim3(BB*EE/32), blk, 0, stream>>>(buf0, vWa, buf1);
    // 3. P = agg * softmax_e(eatt)   (in place in buf1)
    softmax_mul<<<dim3(BB*4), blk, 0, stream>>>(buf1, buf0);
    // 4. edge_feats = P @ vWp^T      -> second output
    rowmm<<<dim3(BB*EE/32), blk, 0, stream>>>(buf1, vWp, edge_out);
    // 5. ef2 = edge_feats @ eWp^T    (right-associated edge_conv)
    rowmm<<<dim3(BB*EE/32), blk, 0, stream>>>(edge_out, eWp, buf0);
    // 6. node_feats = inc @ ef2      (K = E = 2048) -> first output
    big_mm<false><<<dim3(MM/64, BB), blk, 0, stream>>>(inc, buf0, node_out, EE);
}

// Round 2
// 696.762 us; speedup vs baseline: 1.6111x; 1.6111x over previous
//
#include <hip/hip_runtime.h>

#define BB 8
#define MM 4096
#define EE 2048
#define DD 128

typedef _Float16 f16x8 __attribute__((ext_vector_type(8)));
typedef _Float16 f16x4 __attribute__((ext_vector_type(4)));
typedef float    f32x4 __attribute__((ext_vector_type(4)));

// ---------------------------------------------------------------------------
// Transpose kernels: src [R][C] fp32 -> dst [C][R] (f16 or f32), per-batch in
// blockIdx.y. 64x64 tiles, LDS pitch 67 floats (odd -> transposed scalar
// stores spread ~2 lanes/bank).
// ---------------------------------------------------------------------------
__global__ __launch_bounds__(256) void transpose_to16(const float* __restrict__ src,
                                                      _Float16* __restrict__ dst,
                                                      int R, int C)
{
    __shared__ alignas(16) float tile[64 * 67];
    const int tilesC = C >> 6;
    const int r0 = (blockIdx.x / tilesC) << 6;
    const int c0 = (blockIdx.x % tilesC) << 6;
    const float* s = src + (size_t)blockIdx.y * R * C;
    _Float16*   d = dst + (size_t)blockIdx.y * R * C;
    const int t = threadIdx.x;
    #pragma unroll
    for (int i = 0; i < 4; i++){
        int idx = t + 256 * i;
        int r = idx >> 4, c4 = idx & 15;
        float4 v = *(const float4*)(s + (size_t)(r0 + r) * C + c0 + c4 * 4);
        tile[(c4 * 4 + 0) * 67 + r] = v.x;
        tile[(c4 * 4 + 1) * 67 + r] = v.y;
        tile[(c4 * 4 + 2) * 67 + r] = v.z;
        tile[(c4 * 4 + 3) * 67 + r] = v.w;
    }
    __syncthreads();
    #pragma unroll
    for (int i = 0; i < 2; i++){
        int idx = t + 256 * i;
        int row = idx >> 3, rb = idx & 7;
        f16x8 h;
        #pragma unroll
        for (int j = 0; j < 8; j++) h[j] = (_Float16)tile[row * 67 + rb * 8 + j];
        *(f16x8*)(d + (size_t)(c0 + row) * R + r0 + rb * 8) = h;
    }
}

__global__ __launch_bounds__(256) void transpose_f32(const float* __restrict__ src,
                                                     float* __restrict__ dst,
                                                     int R, int C)
{
    __shared__ alignas(16) float tile[64 * 67];
    const int tilesC = C >> 6;
    const int r0 = (blockIdx.x / tilesC) << 6;
    const int c0 = (blockIdx.x % tilesC) << 6;
    const float* s = src + (size_t)blockIdx.y * R * C;
    float*      d = dst + (size_t)blockIdx.y * R * C;
    const int t = threadIdx.x;
    #pragma unroll
    for (int i = 0; i < 4; i++){
        int idx = t + 256 * i;
        int r = idx >> 4, c4 = idx & 15;
        float4 v = *(const float4*)(s + (size_t)(r0 + r) * C + c0 + c4 * 4);
        tile[(c4 * 4 + 0) * 67 + r] = v.x;
        tile[(c4 * 4 + 1) * 67 + r] = v.y;
        tile[(c4 * 4 + 2) * 67 + r] = v.z;
        tile[(c4 * 4 + 3) * 67 + r] = v.w;
    }
    __syncthreads();
    #pragma unroll
    for (int i = 0; i < 4; i++){
        int idx = t + 256 * i;
        int row = idx >> 4, r4 = idx & 15;
        float4 v;
        v.x = tile[row * 67 + r4 * 4 + 0];
        v.y = tile[row * 67 + r4 * 4 + 1];
        v.z = tile[row * 67 + r4 * 4 + 2];
        v.w = tile[row * 67 + r4 * 4 + 3];
        *(float4*)(d + (size_t)(c0 + row) * R + r0 + r4 * 4) = v;
    }
}

// ---------------------------------------------------------------------------
// big1: aggT[b][d][e] = sum_m featT[b][d][m] * inc[b][m][e]
// A = featT (f16, [d][k]-major -> clean b128, XOR-swizzled 16B blocks)
// B = inc (fp32 native [m][e], cvt->f16 staged [k][e] pitch 36; fragment reads
//     are strided ds_read_u16, pitch chosen for <=4-way; kernel is HBM-bound)
// tile: 128 d x 32 e, BK = 64. grid (EE/32, BB) = 512 blocks -> 2/CU.
// ---------------------------------------------------------------------------
__global__ __launch_bounds__(256) void big1(const _Float16* __restrict__ featT,
                                            const float* __restrict__ inc,
                                            float* __restrict__ aggT)
{
    __shared__ alignas(16) _Float16 lA[128 * 64];   // [d][k] XOR-swizzled, 16 KB
    __shared__ alignas(16) _Float16 lB[64 * 36];    // [k=m][e], pitch 36, 4.5 KB
    const int b  = blockIdx.y;
    const int e0 = blockIdx.x * 32;
    const _Float16* fT = featT + (size_t)b * DD * MM;
    const float*    ip = inc   + (size_t)b * MM * EE;
    float*          op = aggT  + (size_t)b * DD * EE;

    const int t = threadIdx.x;
    const int lane = t & 63;
    const int fr = lane & 15, q = lane >> 4;
    const int wd = ((t >> 6) >> 1) * 64;   // wave d-offset {0,64}
    const int we = ((t >> 6) & 1) * 16;    // wave e-offset {0,16}

    f32x4 acc[4] = {};

    uint4  ra[4];
    float4 rb[2];

    auto loadg = [&](int k0){
        #pragma unroll
        for (int i = 0; i < 4; i++){
            int idx = t + 256 * i;
            int dd = idx >> 3, kb = idx & 7;
            ra[i] = *(const uint4*)(fT + (size_t)dd * MM + k0 + kb * 8);
        }
        #pragma unroll
        for (int i = 0; i < 2; i++){
            int idx = t + 256 * i;
            int m = idx >> 3, e4 = idx & 7;
            rb[i] = *(const float4*)(ip + (size_t)(k0 + m) * EE + e0 + e4 * 4);
        }
    };
    auto stores = [&](){
        #pragma unroll
        for (int i = 0; i < 4; i++){
            int idx = t + 256 * i;
            int dd = idx >> 3, kb = idx & 7;
            *(uint4*)&lA[dd * 64 + ((kb ^ (dd & 7)) * 8)] = ra[i];
        }
        #pragma unroll
        for (int i = 0; i < 2; i++){
            int idx = t + 256 * i;
            int m = idx >> 3, e4 = idx & 7;
            f16x4 h = { (_Float16)rb[i].x, (_Float16)rb[i].y,
                        (_Float16)rb[i].z, (_Float16)rb[i].w };
            *(f16x4*)&lB[m * 36 + e4 * 4] = h;
        }
    };

    const int nchunk = MM / 64;
    loadg(0);
    for (int c = 0; c < nchunk; c++){
        __syncthreads();
        stores();
        __syncthreads();
        if (c + 1 < nchunk) loadg((c + 1) * 64);
        #pragma unroll
        for (int h = 0; h < 2; h++){
            f16x8 bfr;
            #pragma unroll
            for (int j = 0; j < 8; j++)
                bfr[j] = lB[(h * 32 + q * 8 + j) * 36 + we + fr];
            const int kb = h * 4 + q;
            #pragma unroll
            for (int r = 0; r < 4; r++){
                int row = wd + r * 16 + fr;
                f16x8 afr = *(const f16x8*)&lA[row * 64 + ((kb ^ (row & 7)) * 8)];
                acc[r] = __builtin_amdgcn_mfma_f32_16x16x32_f16(afr, bfr, acc[r], 0, 0, 0);
            }
        }
    }
    // D layout: col = lane&15, row = quad*4 + reg [m89-verified]
    #pragma unroll
    for (int r = 0; r < 4; r++){
        int drow = wd + r * 16 + q * 4;
        int col  = e0 + we + fr;
        #pragma unroll
        for (int reg = 0; reg < 4; reg++)
            op[(size_t)(drow + reg) * EE + col] = acc[r][reg];
    }
}

// ---------------------------------------------------------------------------
// big2: node[b][m][d] = sum_e inc[b][m][e] * ef2T[b][d][e]
// A = inc native [m][k=e] (cvt->f16), B = ef2T [d][k=e] -- both clean b128
// with XOR swizzle. tile 64 m x 128 d, BK=64. grid (MM/64, BB) = 512 blocks.
// ---------------------------------------------------------------------------
__global__ __launch_bounds__(256) void big2(const float* __restrict__ inc,
                                            const _Float16* __restrict__ ef2T,
                                            float* __restrict__ node)
{
    __shared__ alignas(16) _Float16 lA[64 * 64];    // [m][k] XOR-swizzled, 8 KB
    __shared__ alignas(16) _Float16 lB[128 * 64];   // [d][k] XOR-swizzled, 16 KB
    const int b  = blockIdx.y;
    const int m0 = blockIdx.x * 64;
    const float*    ip = inc  + (size_t)b * MM * EE;
    const _Float16* eT = ef2T + (size_t)b * DD * EE;
    float*          op = node + (size_t)b * MM * DD;

    const int t = threadIdx.x;
    const int lane = t & 63;
    const int fr = lane & 15, q = lane >> 4;
    const int wc = (t >> 6) * 32;   // wave col group

    f32x4 acc[4][2] = {};

    float4 raf[2][2];
    uint4  rbv[4];

    auto loadg = [&](int k0){
        #pragma unroll
        for (int i = 0; i < 2; i++){
            int idx = t + 256 * i;
            int m = idx >> 3, eb = idx & 7;
            raf[i][0] = *(const float4*)(ip + (size_t)(m0 + m) * EE + k0 + eb * 8);
            raf[i][1] = *(const float4*)(ip + (size_t)(m0 + m) * EE + k0 + eb * 8 + 4);
        }
        #pragma unroll
        for (int i = 0; i < 4; i++){
            int idx = t + 256 * i;
            int dd = idx >> 3, kb = idx & 7;
            rbv[i] = *(const uint4*)(eT + (size_t)dd * EE + k0 + kb * 8);
        }
    };
    auto stores = [&](){
        #pragma unroll
        for (int i = 0; i < 2; i++){
            int idx = t + 256 * i;
            int m = idx >> 3, eb = idx & 7;
            f16x8 h;
            h[0] = (_Float16)raf[i][0].x; h[1] = (_Float16)raf[i][0].y;
            h[2] = (_Float16)raf[i][0].z; h[3] = (_Float16)raf[i][0].w;
            h[4] = (_Float16)raf[i][1].x; h[5] = (_Float16)raf[i][1].y;
            h[6] = (_Float16)raf[i][1].z; h[7] = (_Float16)raf[i][1].w;
            *(f16x8*)&lA[m * 64 + ((eb ^ (m & 7)) * 8)] = h;
        }
        #pragma unroll
        for (int i = 0; i < 4; i++){
            int idx = t + 256 * i;
            int dd = idx >> 3, kb = idx & 7;
            *(uint4*)&lB[dd * 64 + ((kb ^ (dd & 7)) * 8)] = rbv[i];
        }
    };

    const int nchunk = EE / 64;
    loadg(0);
    for (int c = 0; c < nchunk; c++){
        __syncthreads();
        stores();
        __syncthreads();
        if (c + 1 < nchunk) loadg((c + 1) * 64);
        #pragma unroll
        for (int h = 0; h < 2; h++){
            const int kb = h * 4 + q;
            f16x8 bfr[2];
            #pragma unroll
            for (int cc = 0; cc < 2; cc++){
                int col = wc + cc * 16 + fr;
                bfr[cc] = *(const f16x8*)&lB[col * 64 + ((kb ^ (col & 7)) * 8)];
            }
            #pragma unroll
            for (int r = 0; r < 4; r++){
                int row = r * 16 + fr;
                f16x8 afr = *(const f16x8*)&lA[row * 64 + ((kb ^ (row & 7)) * 8)];
                #pragma unroll
                for (int cc = 0; cc < 2; cc++)
                    acc[r][cc] = __builtin_amdgcn_mfma_f32_16x16x32_f16(afr, bfr[cc], acc[r][cc], 0, 0, 0);
            }
        }
    }
    #pragma unroll
    for (int r = 0; r < 4; r++)
        #pragma unroll
        for (int cc = 0; cc < 2; cc++){
            int col = wc + cc * 16 + fr;
            #pragma unroll
            for (int reg = 0; reg < 4; reg++)
                op[(size_t)(m0 + r * 16 + q * 4 + reg) * DD + col] = acc[r][cc][reg];
        }
}

// ---------------------------------------------------------------------------
// rowmm (unchanged, verified round 1): C[n,:] = A[n,:] @ W^T, fp32.
// ---------------------------------------------------------------------------
__global__ __launch_bounds__(256) void rowmm(const float* __restrict__ A,
                                             const float* __restrict__ W,
                                             float* __restrict__ C)
{
    __shared__ alignas(16) float lA[32][132];
    __shared__ alignas(16) float lW[64][140];
    const int t = threadIdx.x;
    const int row0 = blockIdx.x * 32;
    const float4* A4 = (const float4*)A;
    const float4* W4 = (const float4*)W;

    #pragma unroll
    for (int i = 0; i < 4; i++){
        int idx = t + 256 * i;
        int r = idx >> 5, k4 = idx & 31;
        *(float4*)&lA[r][k4 * 4] = A4[(size_t)(row0 + r) * 32 + k4];
    }
    const int qq = t >> 5;
    const int cc = t & 31;

    #pragma unroll
    for (int ph = 0; ph < 2; ph++){
        __syncthreads();
        #pragma unroll
        for (int i = 0; i < 8; i++){
            int idx = t + 256 * i;
            int c = idx >> 5, k4 = idx & 31;
            *(float4*)&lW[c][k4 * 4] = W4[(size_t)(ph * 64 + c) * 32 + k4];
        }
        __syncthreads();
        float s[4][2] = {};
        for (int k4 = 0; k4 < 32; k4++){
            float4 w0 = *(const float4*)&lW[cc][k4 * 4];
            float4 w1 = *(const float4*)&lW[cc + 32][k4 * 4];
            #pragma unroll
            for (int j = 0; j < 4; j++){
                float4 a = *(const float4*)&lA[qq + 8 * j][k4 * 4];
                s[j][0] += a.x * w0.x + a.y * w0.y + a.z * w0.z + a.w * w0.w;
                s[j][1] += a.x * w1.x + a.y * w1.y + a.z * w1.z + a.w * w1.w;
            }
        }
        #pragma unroll
        for (int j = 0; j < 4; j++){
            size_t ro = (size_t)(row0 + qq + 8 * j) * DD + ph * 64;
            C[ro + cc]      = s[j][0];
            C[ro + cc + 32] = s[j][1];
        }
    }
}

// ---------------------------------------------------------------------------
// Online softmax over e, two passes, coalesced (d contiguous across lanes).
// sm_part: per (b, slab of 256 e): partial (m, l) per d -> part[b][8][128][2]
// sm_apply: combine partials, P = agg * exp(eatt - m) / l  (in-place on eatt)
// ---------------------------------------------------------------------------
__global__ __launch_bounds__(256) void sm_part(const float* __restrict__ eatt,
                                               float* __restrict__ part)
{
    const int b = blockIdx.x, slab = blockIdx.y;
    const int t = threadIdx.x;
    const int dl = t & 127, eh = t >> 7;
    const size_t base = (size_t)b * EE * DD + dl;
    const int e0 = slab * 256;
    float m = -1e30f;
    for (int s = 0; s < 128; s++)
        m = fmaxf(m, eatt[base + (size_t)(e0 + eh + 2 * s) * DD]);
    float l = 0.f;
    for (int s = 0; s < 128; s++)
        l += __expf(eatt[base + (size_t)(e0 + eh + 2 * s) * DD] - m);
    __shared__ float red[2][128][2];
    red[eh][dl][0] = m; red[eh][dl][1] = l;
    __syncthreads();
    if (t < 128){
        float m0 = red[0][t][0], l0 = red[0][t][1];
        float m1 = red[1][t][0], l1 = red[1][t][1];
        float M = fmaxf(m0, m1);
        float L = l0 * __expf(m0 - M) + l1 * __expf(m1 - M);
        float* p = part + ((size_t)(b * 8 + slab) * DD + t) * 2;
        p[0] = M; p[1] = L;
    }
}

__global__ __launch_bounds__(256) void sm_apply(float* __restrict__ eatt,
                                                const float* __restrict__ agg,
                                                const float* __restrict__ part)
{
    const int b = blockIdx.x, sl = blockIdx.y;
    const int t = threadIdx.x;
    __shared__ float mv[128], iv[128];
    if (t < 128){
        float mbuf[8], lbuf[8];
        float M = -1e30f;
        #pragma unroll
        for (int s = 0; s < 8; s++){
            const float* p = part + ((size_t)(b * 8 + s) * DD + t) * 2;
            mbuf[s] = p[0]; lbuf[s] = p[1];
            M = fmaxf(M, mbuf[s]);
        }
        float L = 0.f;
        #pragma unroll
        for (int s = 0; s < 8; s++) L += lbuf[s] * __expf(mbuf[s] - M);
        mv[t] = M; iv[t] = 1.f / L;
    }
    __syncthreads();
    const int dl = t & 127, eh = t >> 7;
    const size_t base = (size_t)b * EE * DD + dl;
    const int e0 = sl * 128;
    for (int s = 0; s < 64; s++){
        size_t ix = base + (size_t)(e0 + eh + 2 * s) * DD;
        eatt[ix] = agg[ix] * __expf(eatt[ix] - mv[dl]) * iv[dl];
    }
}

// ---------------------------------------------------------------------------
// Pipeline (layer recursion is a fixed point; ec_Wa is dead code):
//  1. featT = T(feat) f16              2. aggT = featT @ inc   (MFMA)
//  3. agg  = T(aggT) f32               4. eatt = agg @ vWa^T
//  5. online softmax -> P (in-place)   6. edge = P @ vWp^T     (output 2)
//  7. ef2  = edge @ eWp^T              8. ef2T = T(ef2) f16
//  9. node = inc @ ef2 via ef2T (MFMA) (output 1)
// Scratch: d_ws = aggT/ef2 [0,8M) + agg/ef2T [8M,16M); d_out node region
// doubles as featT then eatt/P scratch (fully rewritten by big2 at the end);
// part lives at edge region (dead before edge is written).
// ---------------------------------------------------------------------------
extern "C" void kernel_launch(void* const* d_in, const int* in_sizes, int n_in,
                              void* d_out, int out_size, void* d_ws, size_t ws_size,
                              hipStream_t stream)
{
    const float* feat = (const float*)d_in[0];
    const float* inc  = (const float*)d_in[1];
    const float* vWa  = (const float*)d_in[2];
    const float* vWp  = (const float*)d_in[3];
    const float* eWp  = (const float*)d_in[6];

    float* node_out = (float*)d_out;                        // [8,4096,128]
    float* edge_out = node_out + (size_t)BB * MM * DD;      // [8,2048,128]

    _Float16* featT = (_Float16*)node_out;                  // node[0..8M) scratch
    float*    eattP = node_out + (size_t)BB * EE * DD;      // node[8..16M) scratch
    float*    part  = edge_out;                             // 64 KB, dead before step 6

    char* w = (char*)d_ws;
    float* ws1 = (float*)w;                                 // aggT -> ef2   (8 MB)
    float* ws2 = (float*)(w + ((size_t)8 << 20));           // agg  -> ef2T  (8 MB)

    dim3 blk(256);

    // 1. featT[b][d][m] = f16(feat^T)
    transpose_to16<<<dim3((MM / 64) * (DD / 64), BB), blk, 0, stream>>>(feat, featT, MM, DD);
    // 2. aggT = featT @ inc
    big1<<<dim3(EE / 32, BB), blk, 0, stream>>>(featT, inc, ws1);
    // 3. agg[b][e][d] = aggT^T
    transpose_f32<<<dim3((DD / 64) * (EE / 64), BB), blk, 0, stream>>>(ws1, ws2, DD, EE);
    // 4. eatt = agg @ vWa^T   (associativity: (inc^T feat) Wa^T)
    rowmm<<<dim3(BB * EE / 32), blk, 0, stream>>>(ws2, vWa, eattP);
    // 5. P = agg * softmax_e(eatt)
    sm_part <<<dim3(BB, 8),  blk, 0, stream>>>(eattP, part);
    sm_apply<<<dim3(BB, 16), blk, 0, stream>>>(eattP, ws2, part);
    // 6. edge_feats = P @ vWp^T  -> output 2
    rowmm<<<dim3(BB * EE / 32), blk, 0, stream>>>(eattP, vWp, edge_out);
    // 7. ef2 = edge_feats @ eWp^T
    rowmm<<<dim3(BB * EE / 32), blk, 0, stream>>>(edge_out, eWp, ws1);
    // 8. ef2T[b][d][e] = f16(ef2^T)
    transpose_to16<<<dim3((EE / 64) * (DD / 64), BB), blk, 0, stream>>>(ws1, (_Float16*)ws2, EE, DD);
    // 9. node_feats = inc @ ef2  -> output 1
    big2<<<dim3(MM / 64, BB), blk, 0, stream>>>(inc, (const _Float16*)ws2, node_out);
}